// Round 4
// baseline (1372.274 us; speedup 1.0000x reference)
//
#include <hip/hip_runtime.h>
#include <stdint.h>
#include <math.h>

#define N_NODES 100000
#define N_EDGES 1600000
#define IN_DIM 128
#define HID 256
#define N_CLS 40

typedef __attribute__((ext_vector_type(8))) short short8;
typedef __attribute__((ext_vector_type(4))) float f32x4;

__device__ __forceinline__ unsigned short f2bf(float f) {
  unsigned b = __float_as_uint(f);
  b += 0x7fffu + ((b >> 16) & 1u);   // round-to-nearest-even
  return (unsigned short)(b >> 16);
}
__device__ __forceinline__ float bflo(unsigned u) { return __uint_as_float(u << 16); }
__device__ __forceinline__ float bfhi(unsigned u) { return __uint_as_float(u & 0xffff0000u); }

// ---------------------------------------------------------------------------
// zero deg + hist; block 0 detects edge_index dtype (int64 vs int32):
// odd 32-bit words of first 4096 entries all zero => little-endian int64.
// ---------------------------------------------------------------------------
__global__ __launch_bounds__(256) void k_pre0(const unsigned int* __restrict__ ew,
                                              int* __restrict__ flag,
                                              int* __restrict__ deg,
                                              int* __restrict__ hist) {
  int i = blockIdx.x * 256 + threadIdx.x;
  if (i < N_NODES) deg[i] = 0;
  if (blockIdx.x == 1) {
    for (int k = threadIdx.x; k < 1024; k += 256) hist[k] = 0;
  }
  if (blockIdx.x == 0) {
    __shared__ unsigned int sh[256];
    unsigned int v = 0;
    for (int k = threadIdx.x; k < 4096; k += 256) v |= ew[2 * k + 1];
    sh[threadIdx.x] = v;
    __syncthreads();
    for (int s = 128; s > 0; s >>= 1) {
      if (threadIdx.x < s) sh[threadIdx.x] |= sh[threadIdx.x + s];
      __syncthreads();
    }
    if (threadIdx.x == 0) flag[0] = (sh[0] == 0u) ? 1 : 0;
  }
}

__global__ __launch_bounds__(256) void k_convert(const void* __restrict__ eidx,
                                                 const int* __restrict__ flag,
                                                 int* __restrict__ src,
                                                 int* __restrict__ dst,
                                                 int* __restrict__ deg) {
  int k = blockIdx.x * 256 + threadIdx.x;
  if (k >= 2 * N_EDGES) return;
  int vi;
  if (flag[0]) vi = (int)((const long long*)eidx)[k];
  else         vi = ((const int*)eidx)[k];
  if (k < N_EDGES) {
    src[k] = vi;
  } else {
    dst[k - N_EDGES] = vi;
    atomicAdd(&deg[vi], 1);
  }
}

__global__ __launch_bounds__(256) void k_scan1(const int* __restrict__ deg,
                                               int* __restrict__ incl,
                                               int* __restrict__ bsums) {
  __shared__ int sh[256];
  int i = blockIdx.x * 256 + threadIdx.x;
  int v = (i < N_NODES) ? deg[i] : 0;
  sh[threadIdx.x] = v;
  __syncthreads();
  for (int off = 1; off < 256; off <<= 1) {
    int t = (threadIdx.x >= (unsigned)off) ? sh[threadIdx.x - off] : 0;
    __syncthreads();
    sh[threadIdx.x] += t;
    __syncthreads();
  }
  if (i < N_NODES) incl[i] = sh[threadIdx.x];
  if (threadIdx.x == 255) bsums[blockIdx.x] = sh[255];
}

__global__ __launch_bounds__(512) void k_scan2(int* __restrict__ bsums, int nb) {
  __shared__ int sh[512];
  int t = threadIdx.x;
  sh[t] = (t < nb) ? bsums[t] : 0;
  __syncthreads();
  for (int off = 1; off < 512; off <<= 1) {
    int v = (t >= off) ? sh[t - off] : 0;
    __syncthreads();
    sh[t] += v;
    __syncthreads();
  }
  if (t < nb) bsums[t] = (t == 0) ? 0 : sh[t - 1];
}

__global__ __launch_bounds__(256) void k_scan3(const int* __restrict__ deg,
                                               const int* __restrict__ incl,
                                               const int* __restrict__ bsums,
                                               int* __restrict__ row_start,
                                               int* __restrict__ cursor,
                                               float* __restrict__ dinv) {
  int i = blockIdx.x * 256 + threadIdx.x;
  if (i >= N_NODES) return;
  int dg = deg[i];
  int rs = incl[i] - dg + bsums[blockIdx.x];
  row_start[i] = rs;
  cursor[i] = rs;
  dinv[i] = rsqrtf((float)(dg + 1));
  if (i == 0) row_start[N_NODES] = N_EDGES;
}

// counting-sort edges by dst; csr stores src only (weight recomputed via dinv)
__global__ __launch_bounds__(256) void k_fill(const int* __restrict__ src,
                                              const int* __restrict__ dst,
                                              int* __restrict__ cursor,
                                              int* __restrict__ csr_src) {
  int e = blockIdx.x * 256 + threadIdx.x;
  if (e >= N_EDGES) return;
  int s = src[e], d = dst[e];
  int p = atomicAdd(&cursor[d], 1);
  csr_src[p] = s;
}

// ---- degree-sorted node permutation (counting sort, ~equal waves) ----
__global__ __launch_bounds__(256) void k_hist(const int* __restrict__ deg,
                                              int* __restrict__ hist) {
  int i = blockIdx.x * 256 + threadIdx.x;
  if (i >= N_NODES) return;
  atomicAdd(&hist[min(deg[i], 1023)], 1);
}

__global__ __launch_bounds__(1024) void k_hscan(int* __restrict__ hist) {
  __shared__ int sh[1024];
  int t = threadIdx.x;
  sh[t] = hist[t];
  __syncthreads();
  for (int off = 1; off < 1024; off <<= 1) {
    int v = (t >= off) ? sh[t - off] : 0;
    __syncthreads();
    sh[t] += v;
    __syncthreads();
  }
  hist[t] = (t == 0) ? 0 : sh[t - 1];  // exclusive
}

__global__ __launch_bounds__(256) void k_perm(const int* __restrict__ deg,
                                              int* __restrict__ hist,
                                              int* __restrict__ perm) {
  int i = blockIdx.x * 256 + threadIdx.x;
  if (i >= N_NODES) return;
  int p = atomicAdd(&hist[min(deg[i], 1023)], 1);
  perm[p] = i;
}

// ---------------------------------------------------------------------------
// fp32 -> bf16, SLICED layout: slice c = dims [32c, 32c+32), [N][32] shorts
// ---------------------------------------------------------------------------
__global__ __launch_bounds__(256) void k_x2bf_sl(const float* __restrict__ x,
                                                 unsigned short* __restrict__ o,
                                                 int n4) {
  int i = blockIdx.x * 256 + threadIdx.x;
  if (i >= n4) return;
  float4 v = ((const float4*)x)[i];
  ushort4 r;
  r.x = f2bf(v.x); r.y = f2bf(v.y); r.z = f2bf(v.z); r.w = f2bf(v.w);
  int node = i >> 5;               // 32 float4 per 128-dim row
  int d4 = (i & 31) * 4;           // first dim of this float4
  int chunk = d4 >> 5;
  size_t addr = (size_t)chunk * N_NODES * 32 + (size_t)node * 32 + (d4 & 31);
  *(ushort4*)(o + addr) = r;
}

// weight transpose to bf16: W[K][N] -> Bt[Npad][K]
__global__ __launch_bounds__(256) void k_wsplit(const float* __restrict__ W,
                                                int K, int N, int Npad,
                                                unsigned short* __restrict__ Bt) {
  int idx = blockIdx.x * 256 + threadIdx.x;
  if (idx >= Npad * K) return;
  int n = idx / K, k = idx - n * K;
  float w = (n < N) ? W[(size_t)k * N + n] : 0.f;
  Bt[idx] = f2bf(w);
}

// ---------------------------------------------------------------------------
// XCD-sliced gather aggregation. Input: CHUNKS slices of [N][16] uints
// (32 bf16 dims each). Output: row-major [N][CHUNKS*16] uints.
// chunk = blockIdx.x % CHUNKS -> pins slice c's blocks to XCD c (mod 8).
// Wave = 4 nodes x 16 lanes; nodes from degree-sorted perm (balanced).
// Edges batched 16 at a time (coalesced csr load + __shfl broadcast).
// ---------------------------------------------------------------------------
template <int CHUNKS>  // 4 (F=128) or 8 (F=256)
__global__ __launch_bounds__(256) void k_agg_x(const unsigned* __restrict__ slices,
                                               unsigned* __restrict__ out,
                                               const float* __restrict__ dinv,
                                               const int* __restrict__ row_start,
                                               const int* __restrict__ csr_src,
                                               const int* __restrict__ perm) {
  int chunk = blockIdx.x % CHUNKS;
  int nblk  = blockIdx.x / CHUNKS;
  int wave = threadIdx.x >> 6;
  int lane = threadIdx.x & 63;
  int sub = lane >> 4;   // node within wave
  int u   = lane & 15;   // uint within 32-dim chunk
  int slot = nblk * 16 + wave * 4 + sub;
  if (slot >= N_NODES) return;
  int node = perm[slot];
  const unsigned* sl = slices + (size_t)chunk * N_NODES * 16;
  float d = dinv[node];
  unsigned u0 = sl[(size_t)node * 16 + u];
  float d2 = d * d;
  float a0 = bflo(u0) * d2, a1 = bfhi(u0) * d2;
  int e0 = row_start[node], e1 = row_start[node + 1];
  int base_lane = sub * 16;
  int eb = e0;
  for (; eb + 16 <= e1; eb += 16) {
    int sv = csr_src[eb + u];
    float wv = dinv[sv];
#pragma unroll 4
    for (int j = 0; j < 16; j++) {
      int s = __shfl(sv, base_lane + j);
      float w = __shfl(wv, base_lane + j) * d;
      unsigned r = sl[(size_t)s * 16 + u];
      a0 = fmaf(bflo(r), w, a0);
      a1 = fmaf(bfhi(r), w, a1);
    }
  }
  int n_e = e1 - eb;
  if (n_e > 0) {
    int sv = 0; float wv = 0.f;
    if (u < n_e) { sv = csr_src[eb + u]; wv = dinv[sv]; }
    for (int j = 0; j < n_e; j++) {
      int s = __shfl(sv, base_lane + j);
      float w = __shfl(wv, base_lane + j) * d;
      unsigned r = sl[(size_t)s * 16 + u];
      a0 = fmaf(bflo(r), w, a0);
      a1 = fmaf(bfhi(r), w, a1);
    }
  }
  unsigned lo = f2bf(a0), hi = f2bf(a1);
  out[(size_t)node * (CHUNKS * 16) + chunk * 16 + u] = lo | (hi << 16);
}

// ---------------------------------------------------------------------------
// MFMA GEMM: C[M,*] = A[M,K](bf16) @ B[Npad,K]^T (+bias)(+relu)
// 128x128 tile, BK=32, 4 waves 2x2, each wave 64x64 (4x4 mfma 16x16x32).
// SLICED: write C into 32-dim sliced layout (for the next gather stage);
// else row-major with ldc (compact for layer 3).
// ---------------------------------------------------------------------------
template <bool SLICED>
__global__ __launch_bounds__(256) void k_gemm_mfma(const unsigned short* __restrict__ A,
                                                   int lda,
                                                   const unsigned short* __restrict__ B,
                                                   const float* __restrict__ bias,
                                                   unsigned short* __restrict__ C, int ldc,
                                                   int M, int K, int relu) {
  __shared__ alignas(16) unsigned short As[128][40];
  __shared__ alignas(16) unsigned short Bs[128][40];
  int tid = threadIdx.x;
  int lane = tid & 63, wv = tid >> 6;
  int wy = wv >> 1, wx = wv & 1;
  int row0 = blockIdx.x * 128, col0 = blockIdx.y * 128;

  f32x4 acc[4][4];
#pragma unroll
  for (int i = 0; i < 4; i++)
#pragma unroll
    for (int j = 0; j < 4; j++) acc[i][j] = 0.f;

  int sr0 = tid >> 2;
  int sc = (tid & 3) * 8;

  for (int k0 = 0; k0 < K; k0 += 32) {
#pragma unroll
    for (int it = 0; it < 2; it++) {
      int r = sr0 + it * 64;
      int gr = row0 + r;
      short8 va = 0;
      if (gr < M) va = *(const short8*)(A + (size_t)gr * lda + k0 + sc);
      *(short8*)&As[r][sc] = va;
      short8 vb = *(const short8*)(B + (size_t)(col0 + r) * K + k0 + sc);
      *(short8*)&Bs[r][sc] = vb;
    }
    __syncthreads();

    int ar = wy * 64 + (lane & 15);
    int br = wx * 64 + (lane & 15);
    int kk = (lane >> 4) * 8;
    short8 a[4], b[4];
#pragma unroll
    for (int mi = 0; mi < 4; mi++) a[mi] = *(const short8*)&As[ar + mi * 16][kk];
#pragma unroll
    for (int ni = 0; ni < 4; ni++) b[ni] = *(const short8*)&Bs[br + ni * 16][kk];
#pragma unroll
    for (int mi = 0; mi < 4; mi++)
#pragma unroll
      for (int ni = 0; ni < 4; ni++)
        acc[mi][ni] = __builtin_amdgcn_mfma_f32_16x16x32_bf16(a[mi], b[ni], acc[mi][ni], 0, 0, 0);
    __syncthreads();
  }

  int mbase = row0 + wy * 64;
  int nbase = col0 + wx * 64;
#pragma unroll
  for (int ni = 0; ni < 4; ni++) {
    int gc = nbase + ni * 16 + (lane & 15);
    if (!SLICED && gc >= ldc) continue;
    float bz = bias ? bias[gc] : 0.f;
#pragma unroll
    for (int mi = 0; mi < 4; mi++) {
      f32x4 v = acc[mi][ni];
#pragma unroll
      for (int r = 0; r < 4; r++) {
        int gr = mbase + mi * 16 + (lane >> 4) * 4 + r;
        if (gr < M) {
          float o = v[r] + bz;
          if (relu) o = fmaxf(o, 0.f);
          if (SLICED) {
            size_t addr = (size_t)(gc >> 5) * N_NODES * 32 + (size_t)gr * 32 + (gc & 31);
            C[addr] = f2bf(o);
          } else {
            C[(size_t)gr * ldc + gc] = f2bf(o);
          }
        }
      }
    }
  }
}

// ---------------------------------------------------------------------------
// layer-3: gather-agg over compact bf16 logits [N][64] (lane<20, 2 cls/lane)
// + bias + log_softmax, fp32 out. src-only csr, weight via dinv.
// ---------------------------------------------------------------------------
__global__ __launch_bounds__(256) void k_agg40_lsm(const unsigned* __restrict__ in,  // [N][32] uints
                                                   float* __restrict__ out,
                                                   const float* __restrict__ dinv,
                                                   const int* __restrict__ row_start,
                                                   const int* __restrict__ csr_src,
                                                   const int* __restrict__ perm,
                                                   const float* __restrict__ bias) {
  int slot = (blockIdx.x << 2) + (threadIdx.x >> 6);
  int lane = threadIdx.x & 63;
  if (slot >= N_NODES) return;
  int node = perm[slot];
  bool act = lane < 20;
  int cl = act ? lane : 0;
  const unsigned* base = in + cl;
  float d = dinv[node];
  float d2 = d * d;
  unsigned u0 = base[(size_t)node * 32];
  float a0 = bflo(u0) * d2, a1 = bfhi(u0) * d2;
  int e = row_start[node], e1 = row_start[node + 1];
  for (; e + 2 <= e1; e += 2) {
    int s0 = csr_src[e];
    int s1 = csr_src[e + 1];
    unsigned r0 = base[(size_t)s0 * 32];
    unsigned r1 = base[(size_t)s1 * 32];
    float w0 = dinv[s0] * d;
    float w1 = dinv[s1] * d;
    a0 = fmaf(bflo(r0), w0, a0);
    a1 = fmaf(bfhi(r0), w0, a1);
    a0 = fmaf(bflo(r1), w1, a0);
    a1 = fmaf(bfhi(r1), w1, a1);
  }
  if (e < e1) {
    int s0 = csr_src[e];
    unsigned r0 = base[(size_t)s0 * 32];
    float w0 = dinv[s0] * d;
    a0 = fmaf(bflo(r0), w0, a0);
    a1 = fmaf(bfhi(r0), w0, a1);
  }
  float v0 = act ? a0 + bias[2 * lane] : -INFINITY;
  float v1 = act ? a1 + bias[2 * lane + 1] : -INFINITY;
  float m = fmaxf(v0, v1);
  for (int off = 32; off; off >>= 1) m = fmaxf(m, __shfl_down(m, off));
  m = __shfl(m, 0);
  float s = act ? expf(v0 - m) + expf(v1 - m) : 0.f;
  for (int off = 32; off; off >>= 1) s += __shfl_down(s, off);
  s = __shfl(s, 0);
  float lse = m + logf(s);
  if (act) {
    out[(size_t)node * N_CLS + 2 * lane] = v0 - lse;
    out[(size_t)node * N_CLS + 2 * lane + 1] = v1 - lse;
  }
}

// ---------------------------------------------------------------------------
extern "C" void kernel_launch(void* const* d_in, const int* in_sizes, int n_in,
                              void* d_out, int out_size, void* d_ws, size_t ws_size,
                              hipStream_t stream) {
  const float* x  = (const float*)d_in[0];
  const void*  ei = d_in[1];
  const float* W1 = (const float*)d_in[2];
  const float* b1 = (const float*)d_in[3];
  const float* W2 = (const float*)d_in[4];
  const float* b2 = (const float*)d_in[5];
  const float* W3 = (const float*)d_in[6];
  const float* b3 = (const float*)d_in[7];
  float* out = (float*)d_out;

  char* w = (char*)d_ws;
  auto alloc = [&](size_t bytes) {
    char* p = w;
    w += (bytes + 255) & ~(size_t)255;
    return p;
  };
  int*   flag      = (int*)alloc(64);
  int*   src       = (int*)alloc((size_t)N_EDGES * 4);
  int*   dst       = (int*)alloc((size_t)N_EDGES * 4);
  int*   deg       = (int*)alloc((size_t)N_NODES * 4);
  float* dinv      = (float*)alloc((size_t)N_NODES * 4);
  int*   incl      = (int*)alloc((size_t)N_NODES * 4);
  int*   cursor    = (int*)alloc((size_t)N_NODES * 4);
  int*   row_start = (int*)alloc(((size_t)N_NODES + 1) * 4);
  int*   bsums     = (int*)alloc(2048);
  int*   hist      = (int*)alloc(4096);
  int*   perm      = (int*)alloc((size_t)N_NODES * 4);
  int*   csr_src   = (int*)alloc((size_t)N_EDGES * 4);
  unsigned short* Wt1 = (unsigned short*)alloc((size_t)HID * IN_DIM * 2);
  unsigned short* Wt2 = (unsigned short*)alloc((size_t)HID * HID * 2);
  unsigned short* Wt3 = (unsigned short*)alloc((size_t)128 * HID * 2);
  char* R0 = alloc((size_t)N_NODES * HID * 2);  // 51.2 MB
  char* R1 = alloc((size_t)N_NODES * HID * 2);  // 51.2 MB

  unsigned short* xb    = (unsigned short*)R0;                       // [4][N][32] bf16 sliced
  unsigned short* aggX  = (unsigned short*)R0 + (size_t)N_NODES * 128; // [N,128] row-major
  unsigned short* h1    = (unsigned short*)R1;                       // [8][N][32] bf16 sliced
  unsigned short* aggH1 = (unsigned short*)R0;                       // [N,256] row-major
  unsigned short* h2    = (unsigned short*)R1;                       // [N,256] row-major
  unsigned short* C3    = (unsigned short*)R0;                       // [N,64] compact

  const int nb_nodes = (N_NODES + 255) / 256;
  const int nb_conv  = (2 * N_EDGES + 255) / 256;
  const int nb_edges = (N_EDGES + 255) / 256;
  const int nb_n16   = (N_NODES + 15) / 16;      // 6250 node groups of 16
  const int nb_w1    = (N_NODES + 3) / 4;
  const int gm       = (N_NODES + 127) / 128;

  // graph preprocessing
  k_pre0<<<nb_nodes, 256, 0, stream>>>((const unsigned int*)ei, flag, deg, hist);
  k_convert<<<nb_conv, 256, 0, stream>>>(ei, flag, src, dst, deg);
  k_scan1<<<nb_nodes, 256, 0, stream>>>(deg, incl, bsums);
  k_scan2<<<1, 512, 0, stream>>>(bsums, nb_nodes);
  k_scan3<<<nb_nodes, 256, 0, stream>>>(deg, incl, bsums, row_start, cursor, dinv);
  k_fill<<<nb_edges, 256, 0, stream>>>(src, dst, cursor, csr_src);
  k_hist<<<nb_nodes, 256, 0, stream>>>(deg, hist);
  k_hscan<<<1, 1024, 0, stream>>>(hist);
  k_perm<<<nb_nodes, 256, 0, stream>>>(deg, hist, perm);

  // input/weight prep
  k_x2bf_sl<<<(N_NODES * IN_DIM / 4 + 255) / 256, 256, 0, stream>>>(x, xb, N_NODES * IN_DIM / 4);
  k_wsplit<<<(HID * IN_DIM + 255) / 256, 256, 0, stream>>>(W1, IN_DIM, HID, HID, Wt1);
  k_wsplit<<<(HID * HID + 255) / 256, 256, 0, stream>>>(W2, HID, HID, HID, Wt2);
  k_wsplit<<<(128 * HID + 255) / 256, 256, 0, stream>>>(W3, HID, N_CLS, 128, Wt3);

  // layer 1: agg(x) @ W1 + b1, relu  (agg sliced-in, row-major out)
  k_agg_x<4><<<nb_n16 * 4, 256, 0, stream>>>((const unsigned*)xb, (unsigned*)aggX,
                                             dinv, row_start, csr_src, perm);
  k_gemm_mfma<true><<<dim3(gm, HID / 128), 256, 0, stream>>>(aggX, IN_DIM, Wt1, b1,
                                                             h1, HID, N_NODES, IN_DIM, 1);
  // layer 2: agg(h1) @ W2 + b2, relu
  k_agg_x<8><<<nb_n16 * 8, 256, 0, stream>>>((const unsigned*)h1, (unsigned*)aggH1,
                                             dinv, row_start, csr_src, perm);
  k_gemm_mfma<false><<<dim3(gm, HID / 128), 256, 0, stream>>>(aggH1, HID, Wt2, b2,
                                                              h2, HID, N_NODES, HID, 1);
  // layer 3: agg(h2 @ W3) + b3, log_softmax
  k_gemm_mfma<false><<<dim3(gm, 1), 256, 0, stream>>>(h2, HID, Wt3, nullptr,
                                                      C3, 64, N_NODES, HID, 0);
  k_agg40_lsm<<<nb_w1, 256, 0, stream>>>((const unsigned*)C3, out, dinv, row_start,
                                         csr_src, perm, b3);
}

// Round 5
// 1069.023 us; speedup vs baseline: 1.2837x; 1.2837x over previous
//
#include <hip/hip_runtime.h>
#include <stdint.h>
#include <math.h>

#define N_NODES 100000
#define N_EDGES 1600000
#define IN_DIM 128
#define HID 256
#define N_CLS 40

typedef __attribute__((ext_vector_type(8))) short short8;
typedef __attribute__((ext_vector_type(4))) float f32x4;

__device__ __forceinline__ unsigned short f2bf(float f) {
  unsigned b = __float_as_uint(f);
  b += 0x7fffu + ((b >> 16) & 1u);   // round-to-nearest-even
  return (unsigned short)(b >> 16);
}
__device__ __forceinline__ float bflo(unsigned u) { return __uint_as_float(u << 16); }
__device__ __forceinline__ float bfhi(unsigned u) { return __uint_as_float(u & 0xffff0000u); }

// ---------------------------------------------------------------------------
// zero deg + hist; block 0 detects edge_index dtype (int64 vs int32):
// odd 32-bit words of first 4096 entries all zero => little-endian int64.
// ---------------------------------------------------------------------------
__global__ __launch_bounds__(256) void k_pre0(const unsigned int* __restrict__ ew,
                                              int* __restrict__ flag,
                                              int* __restrict__ deg,
                                              int* __restrict__ hist) {
  int i = blockIdx.x * 256 + threadIdx.x;
  if (i < N_NODES) deg[i] = 0;
  if (blockIdx.x == 1) {
    for (int k = threadIdx.x; k < 1024; k += 256) hist[k] = 0;
  }
  if (blockIdx.x == 0) {
    __shared__ unsigned int sh[256];
    unsigned int v = 0;
    for (int k = threadIdx.x; k < 4096; k += 256) v |= ew[2 * k + 1];
    sh[threadIdx.x] = v;
    __syncthreads();
    for (int s = 128; s > 0; s >>= 1) {
      if (threadIdx.x < s) sh[threadIdx.x] |= sh[threadIdx.x + s];
      __syncthreads();
    }
    if (threadIdx.x == 0) flag[0] = (sh[0] == 0u) ? 1 : 0;
  }
}

__global__ __launch_bounds__(256) void k_convert(const void* __restrict__ eidx,
                                                 const int* __restrict__ flag,
                                                 int* __restrict__ src,
                                                 int* __restrict__ dst,
                                                 int* __restrict__ deg) {
  int k = blockIdx.x * 256 + threadIdx.x;
  if (k >= 2 * N_EDGES) return;
  int vi;
  if (flag[0]) vi = (int)((const long long*)eidx)[k];
  else         vi = ((const int*)eidx)[k];
  if (k < N_EDGES) {
    src[k] = vi;
  } else {
    dst[k - N_EDGES] = vi;
    atomicAdd(&deg[vi], 1);
  }
}

__global__ __launch_bounds__(256) void k_scan1(const int* __restrict__ deg,
                                               int* __restrict__ incl,
                                               int* __restrict__ bsums) {
  __shared__ int sh[256];
  int i = blockIdx.x * 256 + threadIdx.x;
  int v = (i < N_NODES) ? deg[i] : 0;
  sh[threadIdx.x] = v;
  __syncthreads();
  for (int off = 1; off < 256; off <<= 1) {
    int t = (threadIdx.x >= (unsigned)off) ? sh[threadIdx.x - off] : 0;
    __syncthreads();
    sh[threadIdx.x] += t;
    __syncthreads();
  }
  if (i < N_NODES) incl[i] = sh[threadIdx.x];
  if (threadIdx.x == 255) bsums[blockIdx.x] = sh[255];
}

__global__ __launch_bounds__(512) void k_scan2(int* __restrict__ bsums, int nb) {
  __shared__ int sh[512];
  int t = threadIdx.x;
  sh[t] = (t < nb) ? bsums[t] : 0;
  __syncthreads();
  for (int off = 1; off < 512; off <<= 1) {
    int v = (t >= off) ? sh[t - off] : 0;
    __syncthreads();
    sh[t] += v;
    __syncthreads();
  }
  if (t < nb) bsums[t] = (t == 0) ? 0 : sh[t - 1];
}

__global__ __launch_bounds__(256) void k_scan3(const int* __restrict__ deg,
                                               const int* __restrict__ incl,
                                               const int* __restrict__ bsums,
                                               int* __restrict__ row_start,
                                               int* __restrict__ cursor,
                                               float* __restrict__ dinv) {
  int i = blockIdx.x * 256 + threadIdx.x;
  if (i >= N_NODES) return;
  int dg = deg[i];
  int rs = incl[i] - dg + bsums[blockIdx.x];
  row_start[i] = rs;
  cursor[i] = rs;
  dinv[i] = rsqrtf((float)(dg + 1));
  if (i == 0) row_start[N_NODES] = N_EDGES;
}

// counting-sort edges by dst; csr stores src only (weight recomputed via dinv)
__global__ __launch_bounds__(256) void k_fill(const int* __restrict__ src,
                                              const int* __restrict__ dst,
                                              int* __restrict__ cursor,
                                              int* __restrict__ csr_src) {
  int e = blockIdx.x * 256 + threadIdx.x;
  if (e >= N_EDGES) return;
  int s = src[e], d = dst[e];
  int p = atomicAdd(&cursor[d], 1);
  csr_src[p] = s;
}

// ---- degree histogram / permutation with BLOCK-LOCAL LDS aggregation ----
// (global-atomic contention fix: <=1 global atomic per (block,bin))
__global__ __launch_bounds__(256) void k_hist(const int* __restrict__ deg,
                                              int* __restrict__ hist) {
  __shared__ int lh[1024];
  int t = threadIdx.x;
  for (int k = t; k < 1024; k += 256) lh[k] = 0;
  __syncthreads();
  int i = blockIdx.x * 256 + t;
  if (i < N_NODES) atomicAdd(&lh[min(deg[i], 1023)], 1);
  __syncthreads();
  for (int k = t; k < 1024; k += 256) {
    int c = lh[k];
    if (c) atomicAdd(&hist[k], c);
  }
}

__global__ __launch_bounds__(1024) void k_hscan(int* __restrict__ hist) {
  __shared__ int sh[1024];
  int t = threadIdx.x;
  sh[t] = hist[t];
  __syncthreads();
  for (int off = 1; off < 1024; off <<= 1) {
    int v = (t >= off) ? sh[t - off] : 0;
    __syncthreads();
    sh[t] += v;
    __syncthreads();
  }
  hist[t] = (t == 0) ? 0 : sh[t - 1];  // exclusive
}

__global__ __launch_bounds__(256) void k_perm(const int* __restrict__ deg,
                                              int* __restrict__ hist,
                                              int* __restrict__ perm) {
  __shared__ int lh[1024];
  __shared__ int lc[1024];
  int t = threadIdx.x;
  for (int k = t; k < 1024; k += 256) lh[k] = 0;
  __syncthreads();
  int i = blockIdx.x * 256 + t;
  int b = -1;
  if (i < N_NODES) {
    b = min(deg[i], 1023);
    atomicAdd(&lh[b], 1);
  }
  __syncthreads();
  for (int k = t; k < 1024; k += 256) {
    int c = lh[k];
    lc[k] = c ? atomicAdd(&hist[k], c) : 0;   // reserve global range for this block
  }
  __syncthreads();
  if (i < N_NODES) {
    int p = atomicAdd(&lc[b], 1);             // LDS cursor within reserved range
    perm[p] = i;
  }
}

// ---------------------------------------------------------------------------
// fp32 -> bf16, 16-dim sliced layout: chunk c = dims [16c,16c+16), [N][16] shorts
// ---------------------------------------------------------------------------
__global__ __launch_bounds__(256) void k_x2bf_sl(const float* __restrict__ x,
                                                 unsigned short* __restrict__ o,
                                                 int n4) {
  int i = blockIdx.x * 256 + threadIdx.x;
  if (i >= n4) return;
  float4 v = ((const float4*)x)[i];
  ushort4 r;
  r.x = f2bf(v.x); r.y = f2bf(v.y); r.z = f2bf(v.z); r.w = f2bf(v.w);
  int node = i >> 5;               // 32 float4 per 128-dim row
  int d4 = (i & 31) * 4;           // first dim of this float4
  int chunk = d4 >> 4;
  size_t addr = (size_t)chunk * N_NODES * 16 + (size_t)node * 16 + (d4 & 15);
  *(ushort4*)(o + addr) = r;
}

// weight transpose to bf16: W[K][N] -> Bt[Npad][K]
__global__ __launch_bounds__(256) void k_wsplit(const float* __restrict__ W,
                                                int K, int N, int Npad,
                                                unsigned short* __restrict__ Bt) {
  int idx = blockIdx.x * 256 + threadIdx.x;
  if (idx >= Npad * K) return;
  int n = idx / K, k = idx - n * K;
  float w = (n < N) ? W[(size_t)k * N + n] : 0.f;
  Bt[idx] = f2bf(w);
}

// ---------------------------------------------------------------------------
// 16-dim-sliced gather aggregation. Input: NCHUNK slices of [N][8] uints
// (16 bf16 dims, 3.2 MB each -> fits one XCD L2). Output row-major [N][NCHUNK*8].
// Block -> (phase, chunk=8*phase + blockIdx%8, nodeblock); consecutive blocks
// cycle chunks 0..7 -> pinned to XCDs via round-robin dispatch; phases are
// temporally separated so each XCD's live slice is 3.2 MB.
// Wave = 8 nodes x 8 lanes; nodes from degree-sorted perm (balanced).
// acc = sum dinv[s]*row_s ; result = d*(acc + d*self)  (d hoisted out of loop)
// ---------------------------------------------------------------------------
template <int NCHUNK>  // 8 (F=128, 1 phase) or 16 (F=256, 2 phases)
__global__ __launch_bounds__(256) void k_agg16(const unsigned* __restrict__ slices,
                                               unsigned* __restrict__ out,
                                               const float* __restrict__ dinv,
                                               const int* __restrict__ row_start,
                                               const int* __restrict__ csr_src,
                                               const int* __restrict__ perm) {
  constexpr int NB = (N_NODES + 31) / 32;  // 3125 node-blocks (exact: 3125*32=100000)
  int q = blockIdx.x;
  int phase = q / (NB * 8);
  int r = q - phase * (NB * 8);
  int chunk = phase * 8 + (r & 7);
  int nblk = r >> 3;
  int wave = threadIdx.x >> 6, lane = threadIdx.x & 63;
  int sub = lane >> 3, u = lane & 7;
  int slot = nblk * 32 + wave * 8 + sub;   // always < N_NODES (exact tiling)
  int node = perm[slot];
  const unsigned* sl = slices + (size_t)chunk * (N_NODES * 8);
  float d = dinv[node];
  unsigned u0 = sl[(size_t)node * 8 + u];
  float a0 = bflo(u0) * d;   // self contribution, pre-scaled by d (one of the two d's)
  float a1 = bfhi(u0) * d;
  int e = row_start[node], e1 = row_start[node + 1];
  for (; e + 2 <= e1; e += 2) {
    int s0 = csr_src[e];
    int s1 = csr_src[e + 1];
    float w0 = dinv[s0];
    float w1 = dinv[s1];
    unsigned r0 = sl[(size_t)s0 * 8 + u];
    unsigned r1 = sl[(size_t)s1 * 8 + u];
    a0 = fmaf(bflo(r0), w0, a0);
    a1 = fmaf(bfhi(r0), w0, a1);
    a0 = fmaf(bflo(r1), w1, a0);
    a1 = fmaf(bfhi(r1), w1, a1);
  }
  if (e < e1) {
    int s0 = csr_src[e];
    float w0 = dinv[s0];
    unsigned r0 = sl[(size_t)s0 * 8 + u];
    a0 = fmaf(bflo(r0), w0, a0);
    a1 = fmaf(bfhi(r0), w0, a1);
  }
  a0 *= d;
  a1 *= d;
  out[(size_t)node * (NCHUNK * 8) + chunk * 8 + u] = f2bf(a0) | ((unsigned)f2bf(a1) << 16);
}

// ---------------------------------------------------------------------------
// MFMA GEMM: C[M,*] = A[M,K](bf16) @ B[Npad,K]^T (+bias)(+relu)
// 128x128 tile, BK=32, 4 waves 2x2, each wave 64x64 (4x4 mfma 16x16x32).
// OUT_SLICED: write C into 16-dim sliced layout; else row-major (cols < ldc).
// ---------------------------------------------------------------------------
template <bool OUT_SLICED>
__global__ __launch_bounds__(256) void k_gemm_mfma(const unsigned short* __restrict__ A,
                                                   int lda,
                                                   const unsigned short* __restrict__ B,
                                                   const float* __restrict__ bias,
                                                   unsigned short* __restrict__ C, int ldc,
                                                   int M, int K, int relu) {
  __shared__ alignas(16) unsigned short As[128][40];
  __shared__ alignas(16) unsigned short Bs[128][40];
  int tid = threadIdx.x;
  int lane = tid & 63, wv = tid >> 6;
  int wy = wv >> 1, wx = wv & 1;
  int row0 = blockIdx.x * 128, col0 = blockIdx.y * 128;

  f32x4 acc[4][4];
#pragma unroll
  for (int i = 0; i < 4; i++)
#pragma unroll
    for (int j = 0; j < 4; j++) acc[i][j] = 0.f;

  int sr0 = tid >> 2;
  int sc = (tid & 3) * 8;

  for (int k0 = 0; k0 < K; k0 += 32) {
#pragma unroll
    for (int it = 0; it < 2; it++) {
      int r = sr0 + it * 64;
      int gr = row0 + r;
      short8 va = 0;
      if (gr < M) va = *(const short8*)(A + (size_t)gr * lda + k0 + sc);
      *(short8*)&As[r][sc] = va;
      short8 vb = *(const short8*)(B + (size_t)(col0 + r) * K + k0 + sc);
      *(short8*)&Bs[r][sc] = vb;
    }
    __syncthreads();

    int ar = wy * 64 + (lane & 15);
    int br = wx * 64 + (lane & 15);
    int kk = (lane >> 4) * 8;
    short8 a[4], b[4];
#pragma unroll
    for (int mi = 0; mi < 4; mi++) a[mi] = *(const short8*)&As[ar + mi * 16][kk];
#pragma unroll
    for (int ni = 0; ni < 4; ni++) b[ni] = *(const short8*)&Bs[br + ni * 16][kk];
#pragma unroll
    for (int mi = 0; mi < 4; mi++)
#pragma unroll
      for (int ni = 0; ni < 4; ni++)
        acc[mi][ni] = __builtin_amdgcn_mfma_f32_16x16x32_bf16(a[mi], b[ni], acc[mi][ni], 0, 0, 0);
    __syncthreads();
  }

  int mbase = row0 + wy * 64;
  int nbase = col0 + wx * 64;
#pragma unroll
  for (int ni = 0; ni < 4; ni++) {
    int gc = nbase + ni * 16 + (lane & 15);
    if (!OUT_SLICED && gc >= ldc) continue;
    float bz = bias ? bias[gc] : 0.f;
#pragma unroll
    for (int mi = 0; mi < 4; mi++) {
      f32x4 v = acc[mi][ni];
#pragma unroll
      for (int r = 0; r < 4; r++) {
        int gr = mbase + mi * 16 + (lane >> 4) * 4 + r;
        if (gr < M) {
          float o = v[r] + bz;
          if (relu) o = fmaxf(o, 0.f);
          if (OUT_SLICED) {
            size_t addr = (size_t)(gc >> 4) * N_NODES * 16 + (size_t)gr * 16 + (gc & 15);
            C[addr] = f2bf(o);
          } else {
            C[(size_t)gr * ldc + gc] = f2bf(o);
          }
        }
      }
    }
  }
}

// ---------------------------------------------------------------------------
// layer-3: gather-agg over compact bf16 logits [N][64] (lane<20, 2 cls/lane)
// + bias + log_softmax, fp32 out. src-only csr, weight via dinv, d hoisted.
// ---------------------------------------------------------------------------
__global__ __launch_bounds__(256) void k_agg40_lsm(const unsigned* __restrict__ in,  // [N][32] uints
                                                   float* __restrict__ out,
                                                   const float* __restrict__ dinv,
                                                   const int* __restrict__ row_start,
                                                   const int* __restrict__ csr_src,
                                                   const int* __restrict__ perm,
                                                   const float* __restrict__ bias) {
  int slot = (blockIdx.x << 2) + (threadIdx.x >> 6);
  int lane = threadIdx.x & 63;
  if (slot >= N_NODES) return;
  int node = perm[slot];
  bool act = lane < 20;
  int cl = act ? lane : 0;
  const unsigned* base = in + cl;
  float d = dinv[node];
  unsigned u0 = base[(size_t)node * 32];
  float a0 = bflo(u0) * d, a1 = bfhi(u0) * d;
  int e = row_start[node], e1 = row_start[node + 1];
  for (; e + 2 <= e1; e += 2) {
    int s0 = csr_src[e];
    int s1 = csr_src[e + 1];
    unsigned r0 = base[(size_t)s0 * 32];
    unsigned r1 = base[(size_t)s1 * 32];
    float w0 = dinv[s0];
    float w1 = dinv[s1];
    a0 = fmaf(bflo(r0), w0, a0);
    a1 = fmaf(bfhi(r0), w0, a1);
    a0 = fmaf(bflo(r1), w1, a0);
    a1 = fmaf(bfhi(r1), w1, a1);
  }
  if (e < e1) {
    int s0 = csr_src[e];
    unsigned r0 = base[(size_t)s0 * 32];
    float w0 = dinv[s0];
    a0 = fmaf(bflo(r0), w0, a0);
    a1 = fmaf(bfhi(r0), w0, a1);
  }
  float v0 = act ? a0 * d + bias[2 * lane] : -INFINITY;
  float v1 = act ? a1 * d + bias[2 * lane + 1] : -INFINITY;
  float m = fmaxf(v0, v1);
  for (int off = 32; off; off >>= 1) m = fmaxf(m, __shfl_down(m, off));
  m = __shfl(m, 0);
  float s = act ? expf(v0 - m) + expf(v1 - m) : 0.f;
  for (int off = 32; off; off >>= 1) s += __shfl_down(s, off);
  s = __shfl(s, 0);
  float lse = m + logf(s);
  if (act) {
    out[(size_t)node * N_CLS + 2 * lane] = v0 - lse;
    out[(size_t)node * N_CLS + 2 * lane + 1] = v1 - lse;
  }
}

// ---------------------------------------------------------------------------
extern "C" void kernel_launch(void* const* d_in, const int* in_sizes, int n_in,
                              void* d_out, int out_size, void* d_ws, size_t ws_size,
                              hipStream_t stream) {
  const float* x  = (const float*)d_in[0];
  const void*  ei = d_in[1];
  const float* W1 = (const float*)d_in[2];
  const float* b1 = (const float*)d_in[3];
  const float* W2 = (const float*)d_in[4];
  const float* b2 = (const float*)d_in[5];
  const float* W3 = (const float*)d_in[6];
  const float* b3 = (const float*)d_in[7];
  float* out = (float*)d_out;

  char* w = (char*)d_ws;
  auto alloc = [&](size_t bytes) {
    char* p = w;
    w += (bytes + 255) & ~(size_t)255;
    return p;
  };
  int*   flag      = (int*)alloc(64);
  int*   src       = (int*)alloc((size_t)N_EDGES * 4);
  int*   dst       = (int*)alloc((size_t)N_EDGES * 4);
  int*   deg       = (int*)alloc((size_t)N_NODES * 4);
  float* dinv      = (float*)alloc((size_t)N_NODES * 4);
  int*   incl      = (int*)alloc((size_t)N_NODES * 4);
  int*   cursor    = (int*)alloc((size_t)N_NODES * 4);
  int*   row_start = (int*)alloc(((size_t)N_NODES + 1) * 4);
  int*   bsums     = (int*)alloc(2048);
  int*   hist      = (int*)alloc(4096);
  int*   perm      = (int*)alloc((size_t)N_NODES * 4);
  int*   csr_src   = (int*)alloc((size_t)N_EDGES * 4);
  unsigned short* Wt1 = (unsigned short*)alloc((size_t)HID * IN_DIM * 2);
  unsigned short* Wt2 = (unsigned short*)alloc((size_t)HID * HID * 2);
  unsigned short* Wt3 = (unsigned short*)alloc((size_t)128 * HID * 2);
  char* R0 = alloc((size_t)N_NODES * HID * 2);  // 51.2 MB
  char* R1 = alloc((size_t)N_NODES * HID * 2);  // 51.2 MB

  unsigned short* xb    = (unsigned short*)R0;                         // [8][N][16] sliced
  unsigned short* aggX  = (unsigned short*)R0 + (size_t)N_NODES * 128; // [N,128] row-major
  unsigned short* h1    = (unsigned short*)R1;                         // [16][N][16] sliced
  unsigned short* aggH1 = (unsigned short*)R0;                         // [N,256] row-major
  unsigned short* h2    = (unsigned short*)R1;                         // [N,256] row-major
  unsigned short* C3    = (unsigned short*)R0;                         // [N,64] compact

  const int nb_nodes = (N_NODES + 255) / 256;
  const int nb_conv  = (2 * N_EDGES + 255) / 256;
  const int nb_edges = (N_EDGES + 255) / 256;
  const int NB       = (N_NODES + 31) / 32;      // 3125
  const int nb_w1    = (N_NODES + 3) / 4;
  const int gm       = (N_NODES + 127) / 128;

  // graph preprocessing
  k_pre0<<<nb_nodes, 256, 0, stream>>>((const unsigned int*)ei, flag, deg, hist);
  k_convert<<<nb_conv, 256, 0, stream>>>(ei, flag, src, dst, deg);
  k_scan1<<<nb_nodes, 256, 0, stream>>>(deg, incl, bsums);
  k_scan2<<<1, 512, 0, stream>>>(bsums, nb_nodes);
  k_scan3<<<nb_nodes, 256, 0, stream>>>(deg, incl, bsums, row_start, cursor, dinv);
  k_fill<<<nb_edges, 256, 0, stream>>>(src, dst, cursor, csr_src);
  k_hist<<<nb_nodes, 256, 0, stream>>>(deg, hist);
  k_hscan<<<1, 1024, 0, stream>>>(hist);
  k_perm<<<nb_nodes, 256, 0, stream>>>(deg, hist, perm);

  // input/weight prep
  k_x2bf_sl<<<(N_NODES * IN_DIM / 4 + 255) / 256, 256, 0, stream>>>(x, xb, N_NODES * IN_DIM / 4);
  k_wsplit<<<(HID * IN_DIM + 255) / 256, 256, 0, stream>>>(W1, IN_DIM, HID, HID, Wt1);
  k_wsplit<<<(HID * HID + 255) / 256, 256, 0, stream>>>(W2, HID, HID, HID, Wt2);
  k_wsplit<<<(128 * HID + 255) / 256, 256, 0, stream>>>(W3, HID, N_CLS, 128, Wt3);

  // layer 1: agg(x) @ W1 + b1, relu  (agg 16-dim sliced in, row-major out)
  k_agg16<8><<<NB * 8, 256, 0, stream>>>((const unsigned*)xb, (unsigned*)aggX,
                                         dinv, row_start, csr_src, perm);
  k_gemm_mfma<true><<<dim3(gm, HID / 128), 256, 0, stream>>>(aggX, IN_DIM, Wt1, b1,
                                                             h1, HID, N_NODES, IN_DIM, 1);
  // layer 2: agg(h1) @ W2 + b2, relu  (two phases of 8 chunks)
  k_agg16<16><<<NB * 16, 256, 0, stream>>>((const unsigned*)h1, (unsigned*)aggH1,
                                           dinv, row_start, csr_src, perm);
  k_gemm_mfma<false><<<dim3(gm, HID / 128), 256, 0, stream>>>(aggH1, HID, Wt2, b2,
                                                              h2, HID, N_NODES, HID, 1);
  // layer 3: agg(h2 @ W3) + b3, log_softmax
  k_gemm_mfma<false><<<dim3(gm, 1), 256, 0, stream>>>(h2, HID, Wt3, nullptr,
                                                      C3, 64, N_NODES, HID, 0);
  k_agg40_lsm<<<nb_w1, 256, 0, stream>>>((const unsigned*)C3, out, dinv, row_start,
                                         csr_src, perm, b3);
}

// Round 6
// 705.249 us; speedup vs baseline: 1.9458x; 1.5158x over previous
//
#include <hip/hip_runtime.h>
#include <stdint.h>
#include <math.h>

#define N_NODES 100000
#define N_EDGES 1600000
#define IN_DIM 128
#define HID 256
#define N_CLS 40

typedef __attribute__((ext_vector_type(8))) short short8;
typedef __attribute__((ext_vector_type(4))) float f32x4;

__device__ __forceinline__ unsigned short f2bf(float f) {
  unsigned b = __float_as_uint(f);
  b += 0x7fffu + ((b >> 16) & 1u);   // round-to-nearest-even
  return (unsigned short)(b >> 16);
}
__device__ __forceinline__ float bflo(unsigned u) { return __uint_as_float(u << 16); }
__device__ __forceinline__ float bfhi(unsigned u) { return __uint_as_float(u & 0xffff0000u); }

// ---------------------------------------------------------------------------
// zero deg; block 0 detects edge_index dtype (int64 vs int32):
// odd 32-bit words of first 4096 entries all zero => little-endian int64.
// ---------------------------------------------------------------------------
__global__ __launch_bounds__(256) void k_pre0(const unsigned int* __restrict__ ew,
                                              int* __restrict__ flag,
                                              int* __restrict__ deg) {
  int i = blockIdx.x * 256 + threadIdx.x;
  if (i < N_NODES) deg[i] = 0;
  if (blockIdx.x == 0) {
    __shared__ unsigned int sh[256];
    unsigned int v = 0;
    for (int k = threadIdx.x; k < 4096; k += 256) v |= ew[2 * k + 1];
    sh[threadIdx.x] = v;
    __syncthreads();
    for (int s = 128; s > 0; s >>= 1) {
      if (threadIdx.x < s) sh[threadIdx.x] |= sh[threadIdx.x + s];
      __syncthreads();
    }
    if (threadIdx.x == 0) flag[0] = (sh[0] == 0u) ? 1 : 0;
  }
}

__global__ __launch_bounds__(256) void k_convert(const void* __restrict__ eidx,
                                                 const int* __restrict__ flag,
                                                 int* __restrict__ src,
                                                 int* __restrict__ dst,
                                                 int* __restrict__ deg) {
  int k = blockIdx.x * 256 + threadIdx.x;
  if (k >= 2 * N_EDGES) return;
  int vi;
  if (flag[0]) vi = (int)((const long long*)eidx)[k];
  else         vi = ((const int*)eidx)[k];
  if (k < N_EDGES) {
    src[k] = vi;
  } else {
    dst[k - N_EDGES] = vi;
    atomicAdd(&deg[vi], 1);
  }
}

__global__ __launch_bounds__(256) void k_scan1(const int* __restrict__ deg,
                                               int* __restrict__ incl,
                                               int* __restrict__ bsums) {
  __shared__ int sh[256];
  int i = blockIdx.x * 256 + threadIdx.x;
  int v = (i < N_NODES) ? deg[i] : 0;
  sh[threadIdx.x] = v;
  __syncthreads();
  for (int off = 1; off < 256; off <<= 1) {
    int t = (threadIdx.x >= (unsigned)off) ? sh[threadIdx.x - off] : 0;
    __syncthreads();
    sh[threadIdx.x] += t;
    __syncthreads();
  }
  if (i < N_NODES) incl[i] = sh[threadIdx.x];
  if (threadIdx.x == 255) bsums[blockIdx.x] = sh[255];
}

__global__ __launch_bounds__(512) void k_scan2(int* __restrict__ bsums, int nb) {
  __shared__ int sh[512];
  int t = threadIdx.x;
  sh[t] = (t < nb) ? bsums[t] : 0;
  __syncthreads();
  for (int off = 1; off < 512; off <<= 1) {
    int v = (t >= off) ? sh[t - off] : 0;
    __syncthreads();
    sh[t] += v;
    __syncthreads();
  }
  if (t < nb) bsums[t] = (t == 0) ? 0 : sh[t - 1];
}

__global__ __launch_bounds__(256) void k_scan3(const int* __restrict__ deg,
                                               const int* __restrict__ incl,
                                               const int* __restrict__ bsums,
                                               int* __restrict__ row_start,
                                               int* __restrict__ cursor,
                                               float* __restrict__ dinv) {
  int i = blockIdx.x * 256 + threadIdx.x;
  if (i >= N_NODES) return;
  int dg = deg[i];
  int rs = incl[i] - dg + bsums[blockIdx.x];
  row_start[i] = rs;
  cursor[i] = rs;
  dinv[i] = rsqrtf((float)(dg + 1));
  if (i == 0) row_start[N_NODES] = N_EDGES;
}

// counting-sort edges by dst; csr stores src only (weight = dinv[s]*dinv[d])
__global__ __launch_bounds__(256) void k_fill(const int* __restrict__ src,
                                              const int* __restrict__ dst,
                                              int* __restrict__ cursor,
                                              int* __restrict__ csr_src) {
  int e = blockIdx.x * 256 + threadIdx.x;
  if (e >= N_EDGES) return;
  int s = src[e], d = dst[e];
  int p = atomicAdd(&cursor[d], 1);
  csr_src[p] = s;
}

// fp32 -> bf16, row-major
__global__ __launch_bounds__(256) void k_x2bf(const float* __restrict__ x,
                                              unsigned short* __restrict__ o,
                                              int n4) {
  int i = blockIdx.x * 256 + threadIdx.x;
  if (i >= n4) return;
  float4 v = ((const float4*)x)[i];
  ushort4 r;
  r.x = f2bf(v.x); r.y = f2bf(v.y); r.z = f2bf(v.z); r.w = f2bf(v.w);
  ((ushort4*)o)[i] = r;
}

// all three weights: transpose + bf16 in one launch
// ranges: [0,32768) W1 K=128,N=256 | [32768,98304) W2 K=256,N=256 |
//         [98304,131072) W3 K=256,Ncls=40,Npad=128
__global__ __launch_bounds__(256) void k_wprep(const float* __restrict__ W1,
                                               const float* __restrict__ W2,
                                               const float* __restrict__ W3,
                                               unsigned short* __restrict__ T1,
                                               unsigned short* __restrict__ T2,
                                               unsigned short* __restrict__ T3) {
  int idx = blockIdx.x * 256 + threadIdx.x;
  if (idx < 32768) {
    int n = idx >> 7, k = idx & 127;               // T1[n][k] = W1[k][n]
    T1[idx] = f2bf(W1[(size_t)k * HID + n]);
  } else if (idx < 98304) {
    int j = idx - 32768;
    int n = j >> 8, k = j & 255;
    T2[j] = f2bf(W2[(size_t)k * HID + n]);
  } else if (idx < 131072) {
    int j = idx - 98304;
    int n = j >> 8, k = j & 255;
    T3[j] = f2bf((n < N_CLS) ? W3[(size_t)k * N_CLS + n] : 0.f);
  }
}

// ---------------------------------------------------------------------------
// Row-major gather aggregation, 256-dim: 1 wave/node, uint2 (4 bf16) per lane,
// edge loop unrolled x4 -> 4 independent 512B row-gathers in flight.
// acc = d*(sum dinv[s]*row_s + d*self)
// ---------------------------------------------------------------------------
__global__ __launch_bounds__(256) void k_agg256(const uint2* __restrict__ in,  // [N][64] uint2
                                                uint2* __restrict__ out,
                                                const float* __restrict__ dinv,
                                                const int* __restrict__ row_start,
                                                const int* __restrict__ csr_src) {
  int node = (blockIdx.x << 2) + (threadIdx.x >> 6);
  int lane = threadIdx.x & 63;
  if (node >= N_NODES) return;
  const uint2* col = in + lane;
  float d = dinv[node];
  uint2 s0 = col[(size_t)node * 64];
  float a0 = bflo(s0.x) * d, a1 = bfhi(s0.x) * d;
  float a2 = bflo(s0.y) * d, a3 = bfhi(s0.y) * d;
  int e = row_start[node], e1 = row_start[node + 1];
  for (; e + 4 <= e1; e += 4) {
    int i0 = csr_src[e], i1 = csr_src[e + 1], i2 = csr_src[e + 2], i3 = csr_src[e + 3];
    float w0 = dinv[i0], w1 = dinv[i1], w2 = dinv[i2], w3 = dinv[i3];
    uint2 r0 = col[(size_t)i0 * 64];
    uint2 r1 = col[(size_t)i1 * 64];
    uint2 r2 = col[(size_t)i2 * 64];
    uint2 r3 = col[(size_t)i3 * 64];
    a0 = fmaf(bflo(r0.x), w0, a0); a1 = fmaf(bfhi(r0.x), w0, a1);
    a2 = fmaf(bflo(r0.y), w0, a2); a3 = fmaf(bfhi(r0.y), w0, a3);
    a0 = fmaf(bflo(r1.x), w1, a0); a1 = fmaf(bfhi(r1.x), w1, a1);
    a2 = fmaf(bflo(r1.y), w1, a2); a3 = fmaf(bfhi(r1.y), w1, a3);
    a0 = fmaf(bflo(r2.x), w2, a0); a1 = fmaf(bfhi(r2.x), w2, a1);
    a2 = fmaf(bflo(r2.y), w2, a2); a3 = fmaf(bfhi(r2.y), w2, a3);
    a0 = fmaf(bflo(r3.x), w3, a0); a1 = fmaf(bfhi(r3.x), w3, a1);
    a2 = fmaf(bflo(r3.y), w3, a2); a3 = fmaf(bfhi(r3.y), w3, a3);
  }
  for (; e < e1; e++) {
    int i0 = csr_src[e];
    float w0 = dinv[i0];
    uint2 r0 = col[(size_t)i0 * 64];
    a0 = fmaf(bflo(r0.x), w0, a0); a1 = fmaf(bfhi(r0.x), w0, a1);
    a2 = fmaf(bflo(r0.y), w0, a2); a3 = fmaf(bfhi(r0.y), w0, a3);
  }
  a0 *= d; a1 *= d; a2 *= d; a3 *= d;
  uint2 o;
  o.x = f2bf(a0) | ((unsigned)f2bf(a1) << 16);
  o.y = f2bf(a2) | ((unsigned)f2bf(a3) << 16);
  out[(size_t)node * 64 + lane] = o;
}

// 128-dim variant: 1 wave/node, uint (2 bf16) per lane, unroll x4.
__global__ __launch_bounds__(256) void k_agg128(const unsigned* __restrict__ in,  // [N][64] uint
                                                unsigned* __restrict__ out,
                                                const float* __restrict__ dinv,
                                                const int* __restrict__ row_start,
                                                const int* __restrict__ csr_src) {
  int node = (blockIdx.x << 2) + (threadIdx.x >> 6);
  int lane = threadIdx.x & 63;
  if (node >= N_NODES) return;
  const unsigned* col = in + lane;
  float d = dinv[node];
  unsigned s0 = col[(size_t)node * 64];
  float a0 = bflo(s0) * d, a1 = bfhi(s0) * d;
  int e = row_start[node], e1 = row_start[node + 1];
  for (; e + 4 <= e1; e += 4) {
    int i0 = csr_src[e], i1 = csr_src[e + 1], i2 = csr_src[e + 2], i3 = csr_src[e + 3];
    float w0 = dinv[i0], w1 = dinv[i1], w2 = dinv[i2], w3 = dinv[i3];
    unsigned r0 = col[(size_t)i0 * 64];
    unsigned r1 = col[(size_t)i1 * 64];
    unsigned r2 = col[(size_t)i2 * 64];
    unsigned r3 = col[(size_t)i3 * 64];
    a0 = fmaf(bflo(r0), w0, a0); a1 = fmaf(bfhi(r0), w0, a1);
    a0 = fmaf(bflo(r1), w1, a0); a1 = fmaf(bfhi(r1), w1, a1);
    a0 = fmaf(bflo(r2), w2, a0); a1 = fmaf(bfhi(r2), w2, a1);
    a0 = fmaf(bflo(r3), w3, a0); a1 = fmaf(bfhi(r3), w3, a1);
  }
  for (; e < e1; e++) {
    int i0 = csr_src[e];
    float w0 = dinv[i0];
    unsigned r0 = col[(size_t)i0 * 64];
    a0 = fmaf(bflo(r0), w0, a0); a1 = fmaf(bfhi(r0), w0, a1);
  }
  a0 *= d; a1 *= d;
  out[(size_t)node * 64 + lane] = f2bf(a0) | ((unsigned)f2bf(a1) << 16);
}

// ---------------------------------------------------------------------------
// MFMA GEMM: C[M,ldc](bf16) = A[M,K](bf16) @ B[Npad,K]^T (+bias)(+relu)
// 128x128 tile, BK=32, 4 waves 2x2, each wave 64x64 (4x4 mfma 16x16x32).
// ---------------------------------------------------------------------------
__global__ __launch_bounds__(256) void k_gemm_mfma(const unsigned short* __restrict__ A,
                                                   int lda,
                                                   const unsigned short* __restrict__ B,
                                                   const float* __restrict__ bias,
                                                   unsigned short* __restrict__ C, int ldc,
                                                   int M, int K, int relu) {
  __shared__ alignas(16) unsigned short As[128][40];
  __shared__ alignas(16) unsigned short Bs[128][40];
  int tid = threadIdx.x;
  int lane = tid & 63, wv = tid >> 6;
  int wy = wv >> 1, wx = wv & 1;
  int row0 = blockIdx.x * 128, col0 = blockIdx.y * 128;

  f32x4 acc[4][4];
#pragma unroll
  for (int i = 0; i < 4; i++)
#pragma unroll
    for (int j = 0; j < 4; j++) acc[i][j] = 0.f;

  int sr0 = tid >> 2;
  int sc = (tid & 3) * 8;

  for (int k0 = 0; k0 < K; k0 += 32) {
#pragma unroll
    for (int it = 0; it < 2; it++) {
      int r = sr0 + it * 64;
      int gr = row0 + r;
      short8 va = 0;
      if (gr < M) va = *(const short8*)(A + (size_t)gr * lda + k0 + sc);
      *(short8*)&As[r][sc] = va;
      short8 vb = *(const short8*)(B + (size_t)(col0 + r) * K + k0 + sc);
      *(short8*)&Bs[r][sc] = vb;
    }
    __syncthreads();

    int ar = wy * 64 + (lane & 15);
    int br = wx * 64 + (lane & 15);
    int kk = (lane >> 4) * 8;
    short8 a[4], b[4];
#pragma unroll
    for (int mi = 0; mi < 4; mi++) a[mi] = *(const short8*)&As[ar + mi * 16][kk];
#pragma unroll
    for (int ni = 0; ni < 4; ni++) b[ni] = *(const short8*)&Bs[br + ni * 16][kk];
#pragma unroll
    for (int mi = 0; mi < 4; mi++)
#pragma unroll
      for (int ni = 0; ni < 4; ni++)
        acc[mi][ni] = __builtin_amdgcn_mfma_f32_16x16x32_bf16(a[mi], b[ni], acc[mi][ni], 0, 0, 0);
    __syncthreads();
  }

  int mbase = row0 + wy * 64;
  int nbase = col0 + wx * 64;
#pragma unroll
  for (int ni = 0; ni < 4; ni++) {
    int gc = nbase + ni * 16 + (lane & 15);
    if (gc >= ldc) continue;
    float bz = bias ? bias[gc] : 0.f;
#pragma unroll
    for (int mi = 0; mi < 4; mi++) {
      f32x4 v = acc[mi][ni];
#pragma unroll
      for (int r = 0; r < 4; r++) {
        int gr = mbase + mi * 16 + (lane >> 4) * 4 + r;
        if (gr < M) {
          float o = v[r] + bz;
          if (relu) o = fmaxf(o, 0.f);
          C[(size_t)gr * ldc + gc] = f2bf(o);
        }
      }
    }
  }
}

// ---------------------------------------------------------------------------
// layer-3: gather-agg over compact bf16 logits [N][64] (lane<20, 2 cls/lane)
// + bias + log_softmax, fp32 out. Unroll x4.
// ---------------------------------------------------------------------------
__global__ __launch_bounds__(256) void k_agg40_lsm(const unsigned* __restrict__ in,  // [N][32] uints
                                                   float* __restrict__ out,
                                                   const float* __restrict__ dinv,
                                                   const int* __restrict__ row_start,
                                                   const int* __restrict__ csr_src,
                                                   const float* __restrict__ bias) {
  int node = (blockIdx.x << 2) + (threadIdx.x >> 6);
  int lane = threadIdx.x & 63;
  if (node >= N_NODES) return;
  bool act = lane < 20;
  int cl = act ? lane : 0;
  const unsigned* base = in + cl;
  float d = dinv[node];
  unsigned u0 = base[(size_t)node * 32];
  float a0 = bflo(u0) * d, a1 = bfhi(u0) * d;
  int e = row_start[node], e1 = row_start[node + 1];
  for (; e + 4 <= e1; e += 4) {
    int i0 = csr_src[e], i1 = csr_src[e + 1], i2 = csr_src[e + 2], i3 = csr_src[e + 3];
    float w0 = dinv[i0], w1 = dinv[i1], w2 = dinv[i2], w3 = dinv[i3];
    unsigned r0 = base[(size_t)i0 * 32];
    unsigned r1 = base[(size_t)i1 * 32];
    unsigned r2 = base[(size_t)i2 * 32];
    unsigned r3 = base[(size_t)i3 * 32];
    a0 = fmaf(bflo(r0), w0, a0); a1 = fmaf(bfhi(r0), w0, a1);
    a0 = fmaf(bflo(r1), w1, a0); a1 = fmaf(bfhi(r1), w1, a1);
    a0 = fmaf(bflo(r2), w2, a0); a1 = fmaf(bfhi(r2), w2, a1);
    a0 = fmaf(bflo(r3), w3, a0); a1 = fmaf(bfhi(r3), w3, a1);
  }
  for (; e < e1; e++) {
    int i0 = csr_src[e];
    float w0 = dinv[i0];
    unsigned r0 = base[(size_t)i0 * 32];
    a0 = fmaf(bflo(r0), w0, a0); a1 = fmaf(bfhi(r0), w0, a1);
  }
  float v0 = act ? a0 * d + bias[2 * lane] : -INFINITY;
  float v1 = act ? a1 * d + bias[2 * lane + 1] : -INFINITY;
  float m = fmaxf(v0, v1);
  for (int off = 32; off; off >>= 1) m = fmaxf(m, __shfl_down(m, off));
  m = __shfl(m, 0);
  float s = act ? expf(v0 - m) + expf(v1 - m) : 0.f;
  for (int off = 32; off; off >>= 1) s += __shfl_down(s, off);
  s = __shfl(s, 0);
  float lse = m + logf(s);
  if (act) {
    out[(size_t)node * N_CLS + 2 * lane] = v0 - lse;
    out[(size_t)node * N_CLS + 2 * lane + 1] = v1 - lse;
  }
}

// ---------------------------------------------------------------------------
extern "C" void kernel_launch(void* const* d_in, const int* in_sizes, int n_in,
                              void* d_out, int out_size, void* d_ws, size_t ws_size,
                              hipStream_t stream) {
  const float* x  = (const float*)d_in[0];
  const void*  ei = d_in[1];
  const float* W1 = (const float*)d_in[2];
  const float* b1 = (const float*)d_in[3];
  const float* W2 = (const float*)d_in[4];
  const float* b2 = (const float*)d_in[5];
  const float* W3 = (const float*)d_in[6];
  const float* b3 = (const float*)d_in[7];
  float* out = (float*)d_out;

  char* w = (char*)d_ws;
  auto alloc = [&](size_t bytes) {
    char* p = w;
    w += (bytes + 255) & ~(size_t)255;
    return p;
  };
  int*   flag      = (int*)alloc(64);
  int*   src       = (int*)alloc((size_t)N_EDGES * 4);
  int*   dst       = (int*)alloc((size_t)N_EDGES * 4);
  int*   deg       = (int*)alloc((size_t)N_NODES * 4);
  float* dinv      = (float*)alloc((size_t)N_NODES * 4);
  int*   incl      = (int*)alloc((size_t)N_NODES * 4);
  int*   cursor    = (int*)alloc((size_t)N_NODES * 4);
  int*   row_start = (int*)alloc(((size_t)N_NODES + 1) * 4);
  int*   bsums     = (int*)alloc(2048);
  int*   csr_src   = (int*)alloc((size_t)N_EDGES * 4);
  unsigned short* Wt1 = (unsigned short*)alloc((size_t)HID * IN_DIM * 2);
  unsigned short* Wt2 = (unsigned short*)alloc((size_t)HID * HID * 2);
  unsigned short* Wt3 = (unsigned short*)alloc((size_t)128 * HID * 2);
  char* R0 = alloc((size_t)N_NODES * HID * 2);  // 51.2 MB
  char* R1 = alloc((size_t)N_NODES * HID * 2);  // 51.2 MB

  unsigned short* xb    = (unsigned short*)R0;                         // [N,128] bf16
  unsigned short* aggX  = (unsigned short*)R0 + (size_t)N_NODES * 128; // [N,128] bf16
  unsigned short* h1    = (unsigned short*)R1;                         // [N,256] bf16
  unsigned short* aggH1 = (unsigned short*)R0;                         // [N,256] (over xb/aggX)
  unsigned short* h2    = (unsigned short*)R1;                         // [N,256] (over h1)
  unsigned short* C3    = (unsigned short*)R0;                         // [N,64]  (over aggH1)

  const int nb_nodes = (N_NODES + 255) / 256;
  const int nb_conv  = (2 * N_EDGES + 255) / 256;
  const int nb_edges = (N_EDGES + 255) / 256;
  const int nb_w1    = (N_NODES + 3) / 4;
  const int gm       = (N_NODES + 127) / 128;

  // graph preprocessing
  k_pre0<<<nb_nodes, 256, 0, stream>>>((const unsigned int*)ei, flag, deg);
  k_convert<<<nb_conv, 256, 0, stream>>>(ei, flag, src, dst, deg);
  k_scan1<<<nb_nodes, 256, 0, stream>>>(deg, incl, bsums);
  k_scan2<<<1, 512, 0, stream>>>(bsums, nb_nodes);
  k_scan3<<<nb_nodes, 256, 0, stream>>>(deg, incl, bsums, row_start, cursor, dinv);
  k_fill<<<nb_edges, 256, 0, stream>>>(src, dst, cursor, csr_src);

  // input/weight prep
  k_x2bf<<<(N_NODES * IN_DIM / 4 + 255) / 256, 256, 0, stream>>>(x, xb, N_NODES * IN_DIM / 4);
  k_wprep<<<(131072 + 255) / 256, 256, 0, stream>>>(W1, W2, W3, Wt1, Wt2, Wt3);

  // layer 1: agg(x) @ W1 + b1, relu
  k_agg128<<<nb_w1, 256, 0, stream>>>((const unsigned*)xb, (unsigned*)aggX,
                                      dinv, row_start, csr_src);
  k_gemm_mfma<<<dim3(gm, HID / 128), 256, 0, stream>>>(aggX, IN_DIM, Wt1, b1,
                                                       h1, HID, N_NODES, IN_DIM, 1);
  // layer 2: agg(h1) @ W2 + b2, relu
  k_agg256<<<nb_w1, 256, 0, stream>>>((const uint2*)h1, (uint2*)aggH1,
                                      dinv, row_start, csr_src);
  k_gemm_mfma<<<dim3(gm, HID / 128), 256, 0, stream>>>(aggH1, HID, Wt2, b2,
                                                       h2, HID, N_NODES, HID, 1);
  // layer 3: agg(h2 @ W3) + b3, log_softmax
  k_gemm_mfma<<<dim3(gm, 1), 256, 0, stream>>>(h2, HID, Wt3, nullptr,
                                               C3, 64, N_NODES, HID, 0);
  k_agg40_lsm<<<nb_w1, 256, 0, stream>>>((const unsigned*)C3, out, dinv, row_start,
                                         csr_src, b3);
}

// Round 7
// 588.669 us; speedup vs baseline: 2.3311x; 1.1980x over previous
//
#include <hip/hip_runtime.h>
#include <stdint.h>
#include <math.h>

#define N_NODES 100000
#define N_EDGES 1600000
#define IN_DIM 128
#define HID 256
#define N_CLS 40
#define NBKT 391                 // buckets of 256 dst nodes: (100000+255)/256
#define NPB 391                  // edge partition blocks: ceil(1.6M/4096)

typedef __attribute__((ext_vector_type(8))) short short8;
typedef __attribute__((ext_vector_type(4))) float f32x4;

__device__ __forceinline__ unsigned short f2bf(float f) {
  unsigned b = __float_as_uint(f);
  b += 0x7fffu + ((b >> 16) & 1u);   // round-to-nearest-even
  return (unsigned short)(b >> 16);
}
__device__ __forceinline__ float bflo(unsigned u) { return __uint_as_float(u << 16); }
__device__ __forceinline__ float bfhi(unsigned u) { return __uint_as_float(u & 0xffff0000u); }

__device__ __forceinline__ int load_idx(const void* eidx, int flag, size_t pos) {
  return flag ? (int)((const long long*)eidx)[pos] : ((const int*)eidx)[pos];
}

// ---------------------------------------------------------------------------
// detect edge_index dtype (odd 32-bit words of first 4096 entries all zero =>
// little-endian int64) + zero the bucket histogram. One block.
// ---------------------------------------------------------------------------
__global__ __launch_bounds__(512) void k_pre0(const unsigned int* __restrict__ ew,
                                              int* __restrict__ flag,
                                              int* __restrict__ hist) {
  int t = threadIdx.x;
  for (int k = t; k < NBKT; k += 512) hist[k] = 0;
  __shared__ unsigned int sh[512];
  unsigned int v = 0;
  for (int k = t; k < 4096; k += 512) v |= ew[2 * k + 1];
  sh[t] = v;
  __syncthreads();
  for (int s = 256; s > 0; s >>= 1) {
    if (t < s) sh[t] |= sh[t + s];
    __syncthreads();
  }
  if (t == 0) flag[0] = (sh[0] == 0u) ? 1 : 0;
}

// ---------------------------------------------------------------------------
// bucket histogram over dst (bucket = dst>>8), LDS-aggregated.
// ---------------------------------------------------------------------------
__global__ __launch_bounds__(256) void k_hist(const void* __restrict__ eidx,
                                              const int* __restrict__ flagp,
                                              int* __restrict__ hist) {
  __shared__ int lh[NBKT];
  int t = threadIdx.x;
  for (int k = t; k < NBKT; k += 256) lh[k] = 0;
  __syncthreads();
  int flag = flagp[0];
  int base = blockIdx.x * 4096;
#pragma unroll
  for (int j = 0; j < 16; j++) {
    int e = base + j * 256 + t;
    if (e < N_EDGES) {
      int d = load_idx(eidx, flag, (size_t)N_EDGES + e);
      atomicAdd(&lh[d >> 8], 1);
    }
  }
  __syncthreads();
  for (int k = t; k < NBKT; k += 256) {
    int c = lh[k];
    if (c) atomicAdd(&hist[k], c);
  }
}

// exclusive scan of 391 buckets -> bucket_start[392], init bucket_cursor
__global__ __launch_bounds__(512) void k_bscan(const int* __restrict__ hist,
                                               int* __restrict__ bucket_start,
                                               int* __restrict__ bucket_cursor) {
  __shared__ int sh[512];
  int t = threadIdx.x;
  int v = (t < NBKT) ? hist[t] : 0;
  sh[t] = v;
  __syncthreads();
  for (int off = 1; off < 512; off <<= 1) {
    int u = (t >= off) ? sh[t - off] : 0;
    __syncthreads();
    sh[t] += u;
    __syncthreads();
  }
  if (t < NBKT) {
    bucket_start[t + 1] = sh[t];
    bucket_cursor[t] = sh[t] - v;
  }
  if (t == 0) bucket_start[0] = 0;
}

// ---------------------------------------------------------------------------
// partition edges into bucket-segmented (src,dst) pairs.
// Per block: LDS count -> one global atomic per (block,bucket) -> scatter.
// Per-(block,bucket) segments are contiguous => near-coalesced writes.
// ---------------------------------------------------------------------------
__global__ __launch_bounds__(256) void k_part(const void* __restrict__ eidx,
                                              const int* __restrict__ flagp,
                                              int* __restrict__ bucket_cursor,
                                              uint2* __restrict__ bpairs) {
  __shared__ int lcur[NBKT];
  int t = threadIdx.x;
  for (int k = t; k < NBKT; k += 256) lcur[k] = 0;
  __syncthreads();
  int flag = flagp[0];
  int base = blockIdx.x * 4096;
#pragma unroll
  for (int j = 0; j < 16; j++) {
    int e = base + j * 256 + t;
    if (e < N_EDGES) {
      int d = load_idx(eidx, flag, (size_t)N_EDGES + e);
      atomicAdd(&lcur[d >> 8], 1);
    }
  }
  __syncthreads();
  for (int k = t; k < NBKT; k += 256) {
    int c = lcur[k];
    int g = c ? atomicAdd(&bucket_cursor[k], c) : 0;
    lcur[k] = g;                       // becomes absolute running cursor
  }
  __syncthreads();
#pragma unroll
  for (int j = 0; j < 16; j++) {
    int e = base + j * 256 + t;
    if (e < N_EDGES) {
      int s = load_idx(eidx, flag, e);
      int d = load_idx(eidx, flag, (size_t)N_EDGES + e);
      int p = atomicAdd(&lcur[d >> 8], 1);
      bpairs[p] = make_uint2((unsigned)s, (unsigned)d);
    }
  }
}

// ---------------------------------------------------------------------------
// per-bucket finalize: local deg -> row_start + dinv + csr placement.
// Block b owns dst nodes [b*256, b*256+256); all its edges are contiguous in
// bpairs. Writes land in a block-contiguous csr region (no amplification).
// ---------------------------------------------------------------------------
__global__ __launch_bounds__(256) void k_bsort(const uint2* __restrict__ bpairs,
                                               const int* __restrict__ bucket_start,
                                               int* __restrict__ row_start,
                                               float* __restrict__ dinv,
                                               int* __restrict__ csr_src) {
  __shared__ int ldeg[256], lsum[256], lcur[256];
  int b = blockIdx.x, t = threadIdx.x;
  int d0 = b << 8;
  int nd = min(256, N_NODES - d0);
  int base = bucket_start[b];
  int n = bucket_start[b + 1] - base;
  ldeg[t] = 0;
  __syncthreads();
  for (int i = t; i < n; i += 256) {
    uint2 p = bpairs[base + i];
    atomicAdd(&ldeg[p.y - d0], 1);
  }
  __syncthreads();
  lsum[t] = ldeg[t];
  __syncthreads();
  for (int off = 1; off < 256; off <<= 1) {
    int v = (t >= off) ? lsum[t - off] : 0;
    __syncthreads();
    lsum[t] += v;
    __syncthreads();
  }
  int excl = lsum[t] - ldeg[t];
  if (t < nd) {
    row_start[d0 + t] = base + excl;
    dinv[d0 + t] = rsqrtf((float)(ldeg[t] + 1));
  }
  lcur[t] = base + excl;
  __syncthreads();
  for (int i = t; i < n; i += 256) {
    uint2 p = bpairs[base + i];
    int pos = atomicAdd(&lcur[p.y - d0], 1);
    csr_src[pos] = (int)p.x;
  }
  if (b == 0 && t == 0) row_start[N_NODES] = N_EDGES;
}

// ---------------------------------------------------------------------------
// merged prep: x -> bf16 (blocks [0, 12500)) ; weight transpose+bf16 (rest)
// ---------------------------------------------------------------------------
__global__ __launch_bounds__(256) void k_prep(const float* __restrict__ x,
                                              unsigned short* __restrict__ xb,
                                              const float* __restrict__ W1,
                                              const float* __restrict__ W2,
                                              const float* __restrict__ W3,
                                              unsigned short* __restrict__ T1,
                                              unsigned short* __restrict__ T2,
                                              unsigned short* __restrict__ T3) {
  const int NX4 = N_NODES * IN_DIM / 4;       // 3.2M float4 -> 12500 blocks
  int i = blockIdx.x * 256 + threadIdx.x;
  if (i < NX4) {
    float4 v = ((const float4*)x)[i];
    ushort4 r;
    r.x = f2bf(v.x); r.y = f2bf(v.y); r.z = f2bf(v.z); r.w = f2bf(v.w);
    ((ushort4*)xb)[i] = r;
    return;
  }
  int idx = i - NX4;
  if (idx < 32768) {
    int n = idx >> 7, k = idx & 127;          // T1[n][k] = W1[k][n]
    T1[idx] = f2bf(W1[(size_t)k * HID + n]);
  } else if (idx < 98304) {
    int j = idx - 32768;
    int n = j >> 8, k = j & 255;
    T2[j] = f2bf(W2[(size_t)k * HID + n]);
  } else if (idx < 131072) {
    int j = idx - 98304;
    int n = j >> 8, k = j & 255;
    T3[j] = f2bf((n < N_CLS) ? W3[(size_t)k * N_CLS + n] : 0.f);
  }
}

// ---------------------------------------------------------------------------
// Row-major gather aggregation, 256-dim: 1 wave/node, uint2 (4 bf16)/lane,
// edge loop unrolled x8 -> 8 independent 512B row-gathers in flight.
// out = d*(sum dinv[s]*row_s + d*self)
// ---------------------------------------------------------------------------
__global__ __launch_bounds__(256) void k_agg256(const uint2* __restrict__ in,  // [N][64]
                                                uint2* __restrict__ out,
                                                const float* __restrict__ dinv,
                                                const int* __restrict__ row_start,
                                                const int* __restrict__ csr_src) {
  int node = (blockIdx.x << 2) + (threadIdx.x >> 6);
  int lane = threadIdx.x & 63;
  if (node >= N_NODES) return;
  const uint2* col = in + lane;
  float d = dinv[node];
  uint2 s0 = col[(size_t)node * 64];
  float a0 = bflo(s0.x) * d, a1 = bfhi(s0.x) * d;
  float a2 = bflo(s0.y) * d, a3 = bfhi(s0.y) * d;
  int e = row_start[node], e1 = row_start[node + 1];
  for (; e + 8 <= e1; e += 8) {
    int i0 = csr_src[e],     i1 = csr_src[e + 1], i2 = csr_src[e + 2], i3 = csr_src[e + 3];
    int i4 = csr_src[e + 4], i5 = csr_src[e + 5], i6 = csr_src[e + 6], i7 = csr_src[e + 7];
    float w0 = dinv[i0], w1 = dinv[i1], w2 = dinv[i2], w3 = dinv[i3];
    float w4 = dinv[i4], w5 = dinv[i5], w6 = dinv[i6], w7 = dinv[i7];
    uint2 r0 = col[(size_t)i0 * 64], r1 = col[(size_t)i1 * 64];
    uint2 r2 = col[(size_t)i2 * 64], r3 = col[(size_t)i3 * 64];
    uint2 r4 = col[(size_t)i4 * 64], r5 = col[(size_t)i5 * 64];
    uint2 r6 = col[(size_t)i6 * 64], r7 = col[(size_t)i7 * 64];
    a0 = fmaf(bflo(r0.x), w0, a0); a1 = fmaf(bfhi(r0.x), w0, a1);
    a2 = fmaf(bflo(r0.y), w0, a2); a3 = fmaf(bfhi(r0.y), w0, a3);
    a0 = fmaf(bflo(r1.x), w1, a0); a1 = fmaf(bfhi(r1.x), w1, a1);
    a2 = fmaf(bflo(r1.y), w1, a2); a3 = fmaf(bfhi(r1.y), w1, a3);
    a0 = fmaf(bflo(r2.x), w2, a0); a1 = fmaf(bfhi(r2.x), w2, a1);
    a2 = fmaf(bflo(r2.y), w2, a2); a3 = fmaf(bfhi(r2.y), w2, a3);
    a0 = fmaf(bflo(r3.x), w3, a0); a1 = fmaf(bfhi(r3.x), w3, a1);
    a2 = fmaf(bflo(r3.y), w3, a2); a3 = fmaf(bfhi(r3.y), w3, a3);
    a0 = fmaf(bflo(r4.x), w4, a0); a1 = fmaf(bfhi(r4.x), w4, a1);
    a2 = fmaf(bflo(r4.y), w4, a2); a3 = fmaf(bfhi(r4.y), w4, a3);
    a0 = fmaf(bflo(r5.x), w5, a0); a1 = fmaf(bfhi(r5.x), w5, a1);
    a2 = fmaf(bflo(r5.y), w5, a2); a3 = fmaf(bfhi(r5.y), w5, a3);
    a0 = fmaf(bflo(r6.x), w6, a0); a1 = fmaf(bfhi(r6.x), w6, a1);
    a2 = fmaf(bflo(r6.y), w6, a2); a3 = fmaf(bfhi(r6.y), w6, a3);
    a0 = fmaf(bflo(r7.x), w7, a0); a1 = fmaf(bfhi(r7.x), w7, a1);
    a2 = fmaf(bflo(r7.y), w7, a2); a3 = fmaf(bfhi(r7.y), w7, a3);
  }
  for (; e < e1; e++) {
    int i0 = csr_src[e];
    float w0 = dinv[i0];
    uint2 r0 = col[(size_t)i0 * 64];
    a0 = fmaf(bflo(r0.x), w0, a0); a1 = fmaf(bfhi(r0.x), w0, a1);
    a2 = fmaf(bflo(r0.y), w0, a2); a3 = fmaf(bfhi(r0.y), w0, a3);
  }
  a0 *= d; a1 *= d; a2 *= d; a3 *= d;
  uint2 o;
  o.x = f2bf(a0) | ((unsigned)f2bf(a1) << 16);
  o.y = f2bf(a2) | ((unsigned)f2bf(a3) << 16);
  out[(size_t)node * 64 + lane] = o;
}

// 128-dim variant: 1 wave/node, uint (2 bf16)/lane, unroll x8.
__global__ __launch_bounds__(256) void k_agg128(const unsigned* __restrict__ in,  // [N][64]
                                                unsigned* __restrict__ out,
                                                const float* __restrict__ dinv,
                                                const int* __restrict__ row_start,
                                                const int* __restrict__ csr_src) {
  int node = (blockIdx.x << 2) + (threadIdx.x >> 6);
  int lane = threadIdx.x & 63;
  if (node >= N_NODES) return;
  const unsigned* col = in + lane;
  float d = dinv[node];
  unsigned s0 = col[(size_t)node * 64];
  float a0 = bflo(s0) * d, a1 = bfhi(s0) * d;
  int e = row_start[node], e1 = row_start[node + 1];
  for (; e + 8 <= e1; e += 8) {
    int i0 = csr_src[e],     i1 = csr_src[e + 1], i2 = csr_src[e + 2], i3 = csr_src[e + 3];
    int i4 = csr_src[e + 4], i5 = csr_src[e + 5], i6 = csr_src[e + 6], i7 = csr_src[e + 7];
    float w0 = dinv[i0], w1 = dinv[i1], w2 = dinv[i2], w3 = dinv[i3];
    float w4 = dinv[i4], w5 = dinv[i5], w6 = dinv[i6], w7 = dinv[i7];
    unsigned r0 = col[(size_t)i0 * 64], r1 = col[(size_t)i1 * 64];
    unsigned r2 = col[(size_t)i2 * 64], r3 = col[(size_t)i3 * 64];
    unsigned r4 = col[(size_t)i4 * 64], r5 = col[(size_t)i5 * 64];
    unsigned r6 = col[(size_t)i6 * 64], r7 = col[(size_t)i7 * 64];
    a0 = fmaf(bflo(r0), w0, a0); a1 = fmaf(bfhi(r0), w0, a1);
    a0 = fmaf(bflo(r1), w1, a0); a1 = fmaf(bfhi(r1), w1, a1);
    a0 = fmaf(bflo(r2), w2, a0); a1 = fmaf(bfhi(r2), w2, a1);
    a0 = fmaf(bflo(r3), w3, a0); a1 = fmaf(bfhi(r3), w3, a1);
    a0 = fmaf(bflo(r4), w4, a0); a1 = fmaf(bfhi(r4), w4, a1);
    a0 = fmaf(bflo(r5), w5, a0); a1 = fmaf(bfhi(r5), w5, a1);
    a0 = fmaf(bflo(r6), w6, a0); a1 = fmaf(bfhi(r6), w6, a1);
    a0 = fmaf(bflo(r7), w7, a0); a1 = fmaf(bfhi(r7), w7, a1);
  }
  for (; e < e1; e++) {
    int i0 = csr_src[e];
    float w0 = dinv[i0];
    unsigned r0 = col[(size_t)i0 * 64];
    a0 = fmaf(bflo(r0), w0, a0); a1 = fmaf(bfhi(r0), w0, a1);
  }
  a0 *= d; a1 *= d;
  out[(size_t)node * 64 + lane] = f2bf(a0) | ((unsigned)f2bf(a1) << 16);
}

// ---------------------------------------------------------------------------
// MFMA GEMM: C[M,ldc](bf16) = A[M,K](bf16) @ B[Npad,K]^T (+bias)(+relu)
// 128x128 tile, BK=32, 4 waves 2x2, each wave 64x64 (4x4 mfma 16x16x32).
// ---------------------------------------------------------------------------
__global__ __launch_bounds__(256) void k_gemm_mfma(const unsigned short* __restrict__ A,
                                                   int lda,
                                                   const unsigned short* __restrict__ B,
                                                   const float* __restrict__ bias,
                                                   unsigned short* __restrict__ C, int ldc,
                                                   int M, int K, int relu) {
  __shared__ alignas(16) unsigned short As[128][40];
  __shared__ alignas(16) unsigned short Bs[128][40];
  int tid = threadIdx.x;
  int lane = tid & 63, wv = tid >> 6;
  int wy = wv >> 1, wx = wv & 1;
  int row0 = blockIdx.x * 128, col0 = blockIdx.y * 128;

  f32x4 acc[4][4];
#pragma unroll
  for (int i = 0; i < 4; i++)
#pragma unroll
    for (int j = 0; j < 4; j++) acc[i][j] = 0.f;

  int sr0 = tid >> 2;
  int sc = (tid & 3) * 8;

  for (int k0 = 0; k0 < K; k0 += 32) {
#pragma unroll
    for (int it = 0; it < 2; it++) {
      int r = sr0 + it * 64;
      int gr = row0 + r;
      short8 va = 0;
      if (gr < M) va = *(const short8*)(A + (size_t)gr * lda + k0 + sc);
      *(short8*)&As[r][sc] = va;
      short8 vb = *(const short8*)(B + (size_t)(col0 + r) * K + k0 + sc);
      *(short8*)&Bs[r][sc] = vb;
    }
    __syncthreads();

    int ar = wy * 64 + (lane & 15);
    int br = wx * 64 + (lane & 15);
    int kk = (lane >> 4) * 8;
    short8 a[4], b[4];
#pragma unroll
    for (int mi = 0; mi < 4; mi++) a[mi] = *(const short8*)&As[ar + mi * 16][kk];
#pragma unroll
    for (int ni = 0; ni < 4; ni++) b[ni] = *(const short8*)&Bs[br + ni * 16][kk];
#pragma unroll
    for (int mi = 0; mi < 4; mi++)
#pragma unroll
      for (int ni = 0; ni < 4; ni++)
        acc[mi][ni] = __builtin_amdgcn_mfma_f32_16x16x32_bf16(a[mi], b[ni], acc[mi][ni], 0, 0, 0);
    __syncthreads();
  }

  int mbase = row0 + wy * 64;
  int nbase = col0 + wx * 64;
#pragma unroll
  for (int ni = 0; ni < 4; ni++) {
    int gc = nbase + ni * 16 + (lane & 15);
    if (gc >= ldc) continue;
    float bz = bias ? bias[gc] : 0.f;
#pragma unroll
    for (int mi = 0; mi < 4; mi++) {
      f32x4 v = acc[mi][ni];
#pragma unroll
      for (int r = 0; r < 4; r++) {
        int gr = mbase + mi * 16 + (lane >> 4) * 4 + r;
        if (gr < M) {
          float o = v[r] + bz;
          if (relu) o = fmaxf(o, 0.f);
          C[(size_t)gr * ldc + gc] = f2bf(o);
        }
      }
    }
  }
}

// ---------------------------------------------------------------------------
// layer-3: gather-agg over compact bf16 logits [N][64] (lane<20, 2 cls/lane)
// + bias + log_softmax, fp32 out. Unroll x8.
// ---------------------------------------------------------------------------
__global__ __launch_bounds__(256) void k_agg40_lsm(const unsigned* __restrict__ in,  // [N][32]
                                                   float* __restrict__ out,
                                                   const float* __restrict__ dinv,
                                                   const int* __restrict__ row_start,
                                                   const int* __restrict__ csr_src,
                                                   const float* __restrict__ bias) {
  int node = (blockIdx.x << 2) + (threadIdx.x >> 6);
  int lane = threadIdx.x & 63;
  if (node >= N_NODES) return;
  bool act = lane < 20;
  int cl = act ? lane : 0;
  const unsigned* base = in + cl;
  float d = dinv[node];
  unsigned u0 = base[(size_t)node * 32];
  float a0 = bflo(u0) * d, a1 = bfhi(u0) * d;
  int e = row_start[node], e1 = row_start[node + 1];
  for (; e + 8 <= e1; e += 8) {
    int i0 = csr_src[e],     i1 = csr_src[e + 1], i2 = csr_src[e + 2], i3 = csr_src[e + 3];
    int i4 = csr_src[e + 4], i5 = csr_src[e + 5], i6 = csr_src[e + 6], i7 = csr_src[e + 7];
    float w0 = dinv[i0], w1 = dinv[i1], w2 = dinv[i2], w3 = dinv[i3];
    float w4 = dinv[i4], w5 = dinv[i5], w6 = dinv[i6], w7 = dinv[i7];
    unsigned r0 = base[(size_t)i0 * 32], r1 = base[(size_t)i1 * 32];
    unsigned r2 = base[(size_t)i2 * 32], r3 = base[(size_t)i3 * 32];
    unsigned r4 = base[(size_t)i4 * 32], r5 = base[(size_t)i5 * 32];
    unsigned r6 = base[(size_t)i6 * 32], r7 = base[(size_t)i7 * 32];
    a0 = fmaf(bflo(r0), w0, a0); a1 = fmaf(bfhi(r0), w0, a1);
    a0 = fmaf(bflo(r1), w1, a0); a1 = fmaf(bfhi(r1), w1, a1);
    a0 = fmaf(bflo(r2), w2, a0); a1 = fmaf(bfhi(r2), w2, a1);
    a0 = fmaf(bflo(r3), w3, a0); a1 = fmaf(bfhi(r3), w3, a1);
    a0 = fmaf(bflo(r4), w4, a0); a1 = fmaf(bfhi(r4), w4, a1);
    a0 = fmaf(bflo(r5), w5, a0); a1 = fmaf(bfhi(r5), w5, a1);
    a0 = fmaf(bflo(r6), w6, a0); a1 = fmaf(bfhi(r6), w6, a1);
    a0 = fmaf(bflo(r7), w7, a0); a1 = fmaf(bfhi(r7), w7, a1);
  }
  for (; e < e1; e++) {
    int i0 = csr_src[e];
    float w0 = dinv[i0];
    unsigned r0 = base[(size_t)i0 * 32];
    a0 = fmaf(bflo(r0), w0, a0); a1 = fmaf(bfhi(r0), w0, a1);
  }
  float v0 = act ? a0 * d + bias[2 * lane] : -INFINITY;
  float v1 = act ? a1 * d + bias[2 * lane + 1] : -INFINITY;
  float m = fmaxf(v0, v1);
  for (int off = 32; off; off >>= 1) m = fmaxf(m, __shfl_down(m, off));
  m = __shfl(m, 0);
  float s = act ? expf(v0 - m) + expf(v1 - m) : 0.f;
  for (int off = 32; off; off >>= 1) s += __shfl_down(s, off);
  s = __shfl(s, 0);
  float lse = m + logf(s);
  if (act) {
    out[(size_t)node * N_CLS + 2 * lane] = v0 - lse;
    out[(size_t)node * N_CLS + 2 * lane + 1] = v1 - lse;
  }
}

// ---------------------------------------------------------------------------
extern "C" void kernel_launch(void* const* d_in, const int* in_sizes, int n_in,
                              void* d_out, int out_size, void* d_ws, size_t ws_size,
                              hipStream_t stream) {
  const float* x  = (const float*)d_in[0];
  const void*  ei = d_in[1];
  const float* W1 = (const float*)d_in[2];
  const float* b1 = (const float*)d_in[3];
  const float* W2 = (const float*)d_in[4];
  const float* b2 = (const float*)d_in[5];
  const float* W3 = (const float*)d_in[6];
  const float* b3 = (const float*)d_in[7];
  float* out = (float*)d_out;

  char* w = (char*)d_ws;
  auto alloc = [&](size_t bytes) {
    char* p = w;
    w += (bytes + 255) & ~(size_t)255;
    return p;
  };
  int*   flag          = (int*)alloc(64);
  int*   hist          = (int*)alloc((size_t)NBKT * 4);
  int*   bucket_start  = (int*)alloc((size_t)(NBKT + 1) * 4);
  int*   bucket_cursor = (int*)alloc((size_t)NBKT * 4);
  uint2* bpairs        = (uint2*)alloc((size_t)N_EDGES * 8);
  int*   csr_src       = (int*)alloc((size_t)N_EDGES * 4);
  int*   row_start     = (int*)alloc(((size_t)N_NODES + 1) * 4);
  float* dinv          = (float*)alloc((size_t)N_NODES * 4);
  unsigned short* Wt1  = (unsigned short*)alloc((size_t)HID * IN_DIM * 2);
  unsigned short* Wt2  = (unsigned short*)alloc((size_t)HID * HID * 2);
  unsigned short* Wt3  = (unsigned short*)alloc((size_t)128 * HID * 2);
  char* R0 = alloc((size_t)N_NODES * HID * 2);  // 51.2 MB
  char* R1 = alloc((size_t)N_NODES * HID * 2);  // 51.2 MB

  unsigned short* xb    = (unsigned short*)R0;                         // [N,128] bf16
  unsigned short* aggX  = (unsigned short*)R0 + (size_t)N_NODES * 128; // [N,128] bf16
  unsigned short* h1    = (unsigned short*)R1;                         // [N,256] bf16
  unsigned short* aggH1 = (unsigned short*)R0;                         // [N,256] (over xb/aggX)
  unsigned short* h2    = (unsigned short*)R1;                         // [N,256] (over h1)
  unsigned short* C3    = (unsigned short*)R0;                         // [N,64]  (over aggH1)

  const int nb_w1 = (N_NODES + 3) / 4;
  const int gm    = (N_NODES + 127) / 128;
  const int nprep = (N_NODES * IN_DIM / 4 + 131072 + 255) / 256;

  // CSR build: detect+zero -> hist -> scan -> partition -> per-bucket finalize
  k_pre0<<<1, 512, 0, stream>>>((const unsigned int*)ei, flag, hist);
  k_hist<<<NPB, 256, 0, stream>>>(ei, flag, hist);
  k_bscan<<<1, 512, 0, stream>>>(hist, bucket_start, bucket_cursor);
  k_part<<<NPB, 256, 0, stream>>>(ei, flag, bucket_cursor, bpairs);
  k_bsort<<<NBKT, 256, 0, stream>>>(bpairs, bucket_start, row_start, dinv, csr_src);

  // input + weight prep (one launch)
  k_prep<<<nprep, 256, 0, stream>>>(x, xb, W1, W2, W3, Wt1, Wt2, Wt3);

  // layer 1: agg(x) @ W1 + b1, relu
  k_agg128<<<nb_w1, 256, 0, stream>>>((const unsigned*)xb, (unsigned*)aggX,
                                      dinv, row_start, csr_src);
  k_gemm_mfma<<<dim3(gm, HID / 128), 256, 0, stream>>>(aggX, IN_DIM, Wt1, b1,
                                                       h1, HID, N_NODES, IN_DIM, 1);
  // layer 2: agg(h1) @ W2 + b2, relu
  k_agg256<<<nb_w1, 256, 0, stream>>>((const uint2*)h1, (uint2*)aggH1,
                                      dinv, row_start, csr_src);
  k_gemm_mfma<<<dim3(gm, HID / 128), 256, 0, stream>>>(aggH1, HID, Wt2, b2,
                                                       h2, HID, N_NODES, HID, 1);
  // layer 3: agg(h2 @ W3) + b3, log_softmax
  k_gemm_mfma<<<dim3(gm, 1), 256, 0, stream>>>(h2, HID, Wt3, nullptr,
                                               C3, 64, N_NODES, HID, 0);
  k_agg40_lsm<<<nb_w1, 256, 0, stream>>>((const unsigned*)C3, out, dinv, row_start,
                                         csr_src, b3);
}